// Round 16
// baseline (239.884 us; speedup 1.0000x reference)
//
#include <hip/hip_runtime.h>
#include <cstdint>
#include <cstddef>

#define EPSV 1e-5f

using f32x4  = __attribute__((ext_vector_type(4))) float;
using bf16x8 = __attribute__((ext_vector_type(8))) short;

// RNE pack of two f32 into two bf16 (lo -> low16, hi -> high16)
static __device__ __forceinline__ unsigned pk2(float lo, float hi) {
    unsigned a = __builtin_bit_cast(unsigned, lo);
    unsigned b = __builtin_bit_cast(unsigned, hi);
    a = (a + 0x7FFFu + ((a >> 16) & 1u)) >> 16;
    b = (b + 0x7FFFu + ((b >> 16) & 1u)) & 0xFFFF0000u;
    return a | b;
}
static __device__ __forceinline__ unsigned short bf16of(float v) {
    return (unsigned short)(pk2(v, 0.f) & 0xFFFFu);
}
static __device__ __forceinline__ float f32of(unsigned short u) {
    return __builtin_bit_cast(float, (unsigned)u << 16);
}
static __device__ __forceinline__ void unpk2(unsigned u, float& lo, float& hi) {
    lo = __builtin_bit_cast(float, u << 16);
    hi = __builtin_bit_cast(float, u & 0xFFFF0000u);
}

// ---------------------------------------------------------------------------
__global__ __launch_bounds__(256) void prep_params(
    const float* __restrict__ rwb, const float* __restrict__ rg,
    const float* __restrict__ rb,  const float* __restrict__ rm,
    const float* __restrict__ rv,
    const float* __restrict__ ewb, const float* __restrict__ eg,
    const float* __restrict__ eb,  const float* __restrict__ em,
    const float* __restrict__ ev,
    const float* __restrict__ bg,  const float* __restrict__ bb,
    const float* __restrict__ bm,  const float* __restrict__ bv,
    float* __restrict__ prm)
{
    int t = threadIdx.x;
    if (t < 128) {
        float sc = rg[t] * rsqrtf(rv[t] + EPSV);
        prm[t]       = sc;
        prm[128 + t] = rb[t] - rm[t] * sc + rwb[t] * sc;
        float bsc = bg[t] * rsqrtf(bv[t] + EPSV);
        prm[768 + t] = bsc;
        prm[896 + t] = bb[t] - bm[t] * bsc;
    }
    {
        float sc = eg[t] * rsqrtf(ev[t] + EPSV);
        prm[256 + t] = sc;
        prm[512 + t] = eb[t] - em[t] * sc + ewb[t] * sc;
    }
}

// ---------------------------------------------------------------------------
// GEMM v3 (round-14, unchanged): pipelined dbuf, BK=32, vectorized I/O.
// ---------------------------------------------------------------------------
#define LDR 40

template<int BMODE, int OUTMODE>
__global__ __launch_bounds__(256) void gemm_v3(
    const void* __restrict__ Bsrc,
    const float* __restrict__ Wt,
    const float* __restrict__ scale,
    const float* __restrict__ shift,
    const float* __restrict__ resid,
    void* __restrict__ OutP,
    int Cin, int O, int P)
{
    const int n    = blockIdx.z;
    const int p0   = blockIdx.x * 64;
    const int o0   = blockIdx.y * 128;
    const int tid  = threadIdx.x;
    const int lane = tid & 63;
    const int wid  = tid >> 6;
    const int wm   = wid >> 1, wn = wid & 1;
    const int rl   = lane & 15;

    constexpr int SMEM = (BMODE == 0)
        ? (20480 + 16384)
        : ((20480 + 10240) < 32768 ? 32768 : (20480 + 10240));
    __shared__ __align__(16) char smem[SMEM];
    short* sA = (short*)smem;             // [2][128*LDR]

    const int ao = tid >> 1;
    const int ak = (tid & 1) * 16;

    f32x4 acc[4][2];
    #pragma unroll
    for (int i = 0; i < 4; ++i)
        #pragma unroll
        for (int j = 0; j < 2; ++j) acc[i][j] = (f32x4)0.f;

    float4 ra[4];
    float4 rb0, rb1;
    uint4  rbu;

    const int nt = Cin >> 5;

    auto load_regs = [&](int t) {
        const int kc = t << 5;
        const float* wrow = Wt + (size_t)(o0 + ao) * Cin + kc + ak;
        #pragma unroll
        for (int i = 0; i < 4; ++i)
            ra[i] = *(const float4*)(wrow + i * 4);
        if constexpr (BMODE == 0) {
            const float* bp = (const float*)Bsrc + (size_t)n * Cin * P;
            int s0 = tid, s1 = tid + 256;
            rb0 = *(const float4*)(bp + (size_t)(kc + (s0 >> 4)) * P + p0 + ((s0 & 15) << 2));
            rb1 = *(const float4*)(bp + (size_t)(kc + (s1 >> 4)) * P + p0 + ((s1 & 15) << 2));
        } else {
            const unsigned short* bp = (const unsigned short*)Bsrc;
            int p = tid >> 2, k8 = (tid & 3) << 3;
            rbu = *(const uint4*)(bp + ((size_t)n * P + p0 + p) * Cin + kc + k8);
        }
    };

    auto write_lds = [&](int buf) {
        short* a = sA + buf * (128 * LDR);
        uint4 w0 = make_uint4(pk2(ra[0].x, ra[0].y), pk2(ra[0].z, ra[0].w),
                              pk2(ra[1].x, ra[1].y), pk2(ra[1].z, ra[1].w));
        uint4 w1 = make_uint4(pk2(ra[2].x, ra[2].y), pk2(ra[2].z, ra[2].w),
                              pk2(ra[3].x, ra[3].y), pk2(ra[3].z, ra[3].w));
        *(uint4*)(a + ao * LDR + ak)     = w0;
        *(uint4*)(a + ao * LDR + ak + 8) = w1;
        if constexpr (BMODE == 0) {
            float* sBf = (float*)(smem + 20480) + buf * 2048;
            int s0 = tid, s1 = tid + 256;
            int k0r = s0 >> 4, p40 = (s0 & 15) << 2;
            int k1r = s1 >> 4, p41 = (s1 & 15) << 2;
            *(float4*)(&sBf[(k0r << 6) + ((p40 + (((k0r >> 3) & 7) << 3)) & 63)]) = rb0;
            *(float4*)(&sBf[(k1r << 6) + ((p41 + (((k1r >> 3) & 7) << 3)) & 63)]) = rb1;
        } else {
            short* sB = (short*)(smem + 20480) + buf * (64 * LDR);
            int p = tid >> 2, k8 = (tid & 3) << 3;
            *(uint4*)(sB + p * LDR + k8) = rbu;
        }
    };

    auto compute = [&](int buf) {
        const short* a = sA + buf * (128 * LDR);
        const int k0 = (lane >> 4) * 8;
        bf16x8 af[4], bfr[2];
        #pragma unroll
        for (int i = 0; i < 4; ++i)
            af[i] = *(const bf16x8*)(a + (wm * 64 + i * 16 + rl) * LDR + k0);
        if constexpr (BMODE == 0) {
            const float* sBf = (const float*)(smem + 20480) + buf * 2048;
            #pragma unroll
            for (int j = 0; j < 2; ++j) {
                int p = wn * 32 + j * 16 + rl;
                int base = (p + ((k0 >> 3) << 3)) & 63;
                float f[8];
                #pragma unroll
                for (int q = 0; q < 8; ++q)
                    f[q] = sBf[((k0 + q) << 6) + base];
                uint4 u = make_uint4(pk2(f[0], f[1]), pk2(f[2], f[3]),
                                     pk2(f[4], f[5]), pk2(f[6], f[7]));
                bfr[j] = __builtin_bit_cast(bf16x8, u);
            }
        } else {
            const short* sB = (const short*)(smem + 20480) + buf * (64 * LDR);
            #pragma unroll
            for (int j = 0; j < 2; ++j)
                bfr[j] = *(const bf16x8*)(sB + (wn * 32 + j * 16 + rl) * LDR + k0);
        }
        #pragma unroll
        for (int i = 0; i < 4; ++i)
            #pragma unroll
            for (int j = 0; j < 2; ++j)
                acc[i][j] = __builtin_amdgcn_mfma_f32_16x16x32_bf16(
                    af[i], bfr[j], acc[i][j], 0, 0, 0);
    };

    load_regs(0);
    write_lds(0);
    for (int t = 0; t < nt; ++t) {
        if (t + 1 < nt) load_regs(t + 1);
        __syncthreads();
        compute(t & 1);
        if (t + 1 < nt) write_lds((t + 1) & 1);
    }

    if constexpr (OUTMODE == 1) {
        __syncthreads();
        unsigned short* eL = (unsigned short*)smem;   // [64 p][128 o]
        #pragma unroll
        for (int i = 0; i < 4; ++i) {
            #pragma unroll
            for (int r = 0; r < 4; ++r) {
                int ol = wm * 64 + i * 16 + (lane >> 4) * 4 + r;
                int o  = o0 + ol;
                float sc = scale[o], sh = shift[o];
                #pragma unroll
                for (int j = 0; j < 2; ++j) {
                    int p = wn * 32 + j * 16 + rl;
                    float v = fmaxf(fmaf(acc[i][j][r], sc, sh), 0.f);
                    eL[p * 128 + (ol ^ ((p & 15) << 3))] = bf16of(v);
                }
            }
        }
        __syncthreads();
        unsigned short* out = (unsigned short*)OutP;
        #pragma unroll
        for (int it = 0; it < 4; ++it) {
            int idx = tid + it * 256;
            int p = idx >> 4, m = idx & 15;
            uint4 u = *(const uint4*)(&eL[p * 128 + ((m ^ (p & 15)) << 3)]);
            *(uint4*)(out + ((size_t)n * P + p0 + p) * O + (m << 3)) = u;
        }
    } else {
        __syncthreads();
        float* eT = (float*)smem;                     // [128 o][64 p] rotated
        #pragma unroll
        for (int i = 0; i < 4; ++i) {
            #pragma unroll
            for (int r = 0; r < 4; ++r) {
                int ol = wm * 64 + i * 16 + (lane >> 4) * 4 + r;
                int o  = o0 + ol;
                float sc = scale[o], sh = shift[o];
                #pragma unroll
                for (int j = 0; j < 2; ++j) {
                    int p = wn * 32 + j * 16 + rl;
                    eT[(ol << 6) + ((p + ((ol & 7) << 3)) & 63)] =
                        fmaf(acc[i][j][r], sc, sh);
                }
            }
        }
        __syncthreads();
        float* out = (float*)OutP;
        #pragma unroll
        for (int it = 0; it < 8; ++it) {
            int idx = tid + it * 256;
            int ol = idx >> 4, p4 = (idx & 15) << 2;
            float4 v = *(const float4*)(&eT[(ol << 6) + ((p4 + ((ol & 7) << 3)) & 63)]);
            size_t base = ((size_t)n * O + o0 + ol) * P + p0 + p4;
            if (resid) {
                float4 r4 = *(const float4*)(resid + base);
                v.x += r4.x; v.y += r4.y; v.z += r4.z; v.w += r4.w;
            }
            v.x = fmaxf(v.x, 0.f); v.y = fmaxf(v.y, 0.f);
            v.z = fmaxf(v.z, 0.f); v.w = fmaxf(v.w, 0.f);
            *(float4*)(out + base) = v;
        }
    }
}

// ---------------------------------------------------------------------------
// Fused res2net chain, 512 threads: thread owns (c, t, h); h splits the 25-v
// range 13/12. Mix partials are combined with a WAVE-UNIFORM-index
// __shfl_xor(.,32) over all 25 w (fix for round-15's mismatched-index bug).
// ---------------------------------------------------------------------------
__global__ __launch_bounds__(512) void gcn_fused(
    const unsigned short* __restrict__ hT,
    unsigned short* __restrict__ outsT,
    const float* __restrict__ gw,
    const float* __restrict__ gb,
    const float* __restrict__ Aadj,
    const float* __restrict__ PA,
    const float* __restrict__ bsc4,
    const float* __restrict__ bsh4)
{
    const int n  = blockIdx.y;
    const int tt = blockIdx.x;
    const int tid = threadIdx.x;
    const int c  = tid & 31;
    const int h  = (tid >> 5) & 1;
    const int t  = tid >> 6;            // 0..7
    const int v0 = h * 13;
    const int nv = 13 - h;              // 13 or 12

    __shared__ unsigned short spb[200 * 32];    // 12,800 B
    __shared__ float wsg[96 * 33];              // 12,672 B
    __shared__ float Mm[3][25][28];             //  8,400 B
    __shared__ unsigned short outb[200 * 32];   // 12,800 B

    const size_t rowbase = (size_t)n * 1600 + (size_t)tt * 200;

    {
        const unsigned short* hrow = hT + rowbase * 128;
        for (int idx = tid; idx < 800; idx += 512) {
            int p = idx >> 2, c8 = (idx & 3) << 3;
            *(uint4*)(&spb[p * 32 + c8]) =
                *(const uint4*)(hrow + (size_t)p * 128 + c8);
        }
        for (int idx = tid; idx < 96 * 32; idx += 512)
            wsg[(idx >> 5) * 33 + (idx & 31)] = gw[idx];
        for (int idx = tid; idx < 1875; idx += 512) {
            int k = idx / 625, rem = idx % 625;
            Mm[k][rem / 25][rem % 25] = Aadj[idx] + PA[idx];
        }
    }
    __syncthreads();

    for (int step = 0; step < 4; ++step) {
        // ---- conv 32->96 on own v-half (LDS broadcast reads) ----
        float g[3][13];
        {
            const float* gbp = gb + step * 96;
            float b0 = gbp[c], b1 = gbp[32 + c], b2 = gbp[64 + c];
            #pragma unroll
            for (int v = 0; v < 13; ++v) { g[0][v] = b0; g[1][v] = b1; g[2][v] = b2; }
        }
        const unsigned short* srow = spb + (t * 25 + v0) * 32;
        for (int cin = 0; cin < 32; ++cin) {
            float w0 = wsg[c * 33 + cin];
            float w1 = wsg[(32 + c) * 33 + cin];
            float w2 = wsg[(64 + c) * 33 + cin];
            #pragma unroll
            for (int v = 0; v < 13; ++v) {
                if (v < nv) {
                    float sv = f32of(srow[v * 32 + cin]);
                    g[0][v] = fmaf(w0, sv, g[0][v]);
                    g[1][v] = fmaf(w1, sv, g[1][v]);
                    g[2][v] = fmaf(w2, sv, g[2][v]);
                }
            }
        }

        // ---- adjacency mix: own-v partial over all 25 w ----
        float part[25];
        #pragma unroll
        for (int w = 0; w < 25; ++w) part[w] = 0.f;
        #pragma unroll
        for (int k = 0; k < 3; ++k)
            #pragma unroll
            for (int v = 0; v < 13; ++v) {
                if (v < nv) {
                    float gv = g[k][v];
                    #pragma unroll
                    for (int w = 0; w < 25; ++w)
                        part[w] = fmaf(gv, Mm[k][v0 + v][w], part[w]);
                }
            }

        // ---- combine halves (WAVE-UNIFORM shuffle index) + BN + ReLU ----
        float out[13];
        float sc = bsc4[step * 32 + c], sh = bsh4[step * 32 + c];
        #pragma unroll
        for (int wg = 0; wg < 25; ++wg) {
            float full = part[wg] + __shfl_xor(part[wg], 32);
            int w = wg - v0;
            if (w >= 0 && w < nv)
                out[w] = fmaxf(fmaf(full, sc, sh), 0.f);
        }

        __syncthreads();   // conv/mix reads of spb, wsg, Mm complete

        // ---- commit own (c, t, w-half): spb = out, outb = out ----
        #pragma unroll
        for (int w = 0; w < 13; ++w) {
            if (w < nv) {
                unsigned short b = bf16of(out[w]);
                int p = t * 25 + v0 + w;
                spb[p * 32 + c]  = b;
                outb[p * 32 + c] = b;
            }
        }
        __syncthreads();

        {
            unsigned short* orow = outsT + rowbase * 128 + step * 32;
            for (int idx = tid; idx < 800; idx += 512) {
                int p = idx >> 2, c8 = (idx & 3) << 3;
                uint4 u = *(const uint4*)(&outb[p * 32 + c8]);
                *(uint4*)(orow + (size_t)p * 128 + c8) = u;
            }
        }

        if (step < 3) {
            const unsigned short* hrow = hT + rowbase * 128 + (step + 1) * 32;
            for (int idx = tid; idx < 800; idx += 512) {
                int p = idx >> 2, c8 = (idx & 3) << 3;
                uint4 u = *(const uint4*)(hrow + (size_t)p * 128 + c8);
                uint4 s = *(const uint4*)(&spb[p * 32 + c8]);
                float hf[8], sf[8];
                unpk2(u.x, hf[0], hf[1]); unpk2(u.y, hf[2], hf[3]);
                unpk2(u.z, hf[4], hf[5]); unpk2(u.w, hf[6], hf[7]);
                unpk2(s.x, sf[0], sf[1]); unpk2(s.y, sf[2], sf[3]);
                unpk2(s.z, sf[4], sf[5]); unpk2(s.w, sf[6], sf[7]);
                uint4 r = make_uint4(pk2(sf[0] + hf[0], sf[1] + hf[1]),
                                     pk2(sf[2] + hf[2], sf[3] + hf[3]),
                                     pk2(sf[4] + hf[4], sf[5] + hf[5]),
                                     pk2(sf[6] + hf[6], sf[7] + hf[7]));
                *(uint4*)(&spb[p * 32 + c8]) = r;
            }
            const float* gwp = gw + (step + 1) * 96 * 32;
            for (int idx = tid; idx < 96 * 32; idx += 512)
                wsg[(idx >> 5) * 33 + (idx & 31)] = gwp[idx];
            const float* pap = PA + (step + 1) * 1875;
            for (int idx = tid; idx < 1875; idx += 512) {
                int k = idx / 625, rem = idx % 625;
                Mm[k][rem / 25][rem % 25] = Aadj[idx] + pap[idx];
            }
            __syncthreads();
        }
    }
}

// ---------------------------------------------------------------------------
extern "C" void kernel_launch(void* const* d_in, const int* in_sizes, int n_in,
                              void* d_out, int out_size, void* d_ws, size_t ws_size,
                              hipStream_t stream)
{
    const float* x   = (const float*)d_in[0];
    const float* A   = (const float*)d_in[1];
    const float* rw  = (const float*)d_in[2];
    const float* rwb = (const float*)d_in[3];
    const float* rg  = (const float*)d_in[4];
    const float* rb  = (const float*)d_in[5];
    const float* rm  = (const float*)d_in[6];
    const float* rv  = (const float*)d_in[7];
    const float* gw  = (const float*)d_in[8];
    const float* gb  = (const float*)d_in[9];
    const float* PA  = (const float*)d_in[10];
    const float* bg  = (const float*)d_in[11];
    const float* bb  = (const float*)d_in[12];
    const float* bm  = (const float*)d_in[13];
    const float* bv  = (const float*)d_in[14];
    const float* ew  = (const float*)d_in[15];
    const float* ewb = (const float*)d_in[16];
    const float* eg  = (const float*)d_in[17];
    const float* eb  = (const float*)d_in[18];
    const float* em  = (const float*)d_in[19];
    const float* ev  = (const float*)d_in[20];

    char* wsb = (char*)d_ws;
    unsigned short* hT    = (unsigned short*)wsb;               // 26,214,400 B
    unsigned short* outsT = (unsigned short*)(wsb + 26214400);  // 26,214,400 B
    float*          prm   = (float*)(wsb + 52428800);           // 4 KB

    prep_params<<<1, 256, 0, stream>>>(rwb, rg, rb, rm, rv,
                                       ewb, eg, eb, em, ev,
                                       bg, bb, bm, bv, prm);

    // reduct: x f32 [n][256][1600] -> hT bf16 [n][1600][128]
    gemm_v3<0, 1><<<dim3(25, 1, 64), 256, 0, stream>>>(
        x, rw, prm, prm + 128, nullptr, hT, 256, 128, 1600);

    // fused res2net chain (4 steps, one launch, 512 threads)
    gcn_fused<<<dim3(8, 64), 512, 0, stream>>>(
        hT, outsT, gw, gb, A, PA, prm + 768, prm + 896);

    // expand: outsT bf16 -> d_out f32 [n][256][1600] (+x residual)
    gemm_v3<1, 0><<<dim3(25, 2, 64), 256, 0, stream>>>(
        outsT, ew, prm + 256, prm + 512, x, d_out, 128, 256, 1600);
}